// Round 6
// baseline (722.082 us; speedup 1.0000x reference)
//
#include <hip/hip_runtime.h>

#define B_ 256
#define D_ 784
#define V_ 128
#define S_ 2
#define BD (B_ * D_)
#define KSPLIT 8
#define KC 98                      // 784 / 8
#define NJOBS (4 * 13 * KSPLIT)    // 416 gemm tile-jobs
#define JOBS_PER_BT (13 * KSPLIT)  // 104 jobs per 64-row group
#define NBLK_FUSED (NJOBS + B_)    // 672
#define SUBSZ 2368                 // 64*20 + 16*68 floats
#define AGENT __HIP_MEMORY_SCOPE_AGENT

__device__ __forceinline__ void get_params(const int* kiter, float& ss, float& bal) {
    int k = kiter[0] % 10;
    ss  = (k == 0) ? 0.5f : 0.1f;
    bal = (k == 0) ? 0.9f : 0.6f;
}

__device__ __forceinline__ double wave_red(double v) {
#pragma unroll
    for (int o = 32; o > 0; o >>= 1) v += __shfl_down(v, o, 64);
    return v;
}

// ---------------------------------------------------------------------------
// forward per-element: windowed categorical + lse. Returns lch-lse, imax.
// (identical arithmetic to round-1 forward_k)
// ---------------------------------------------------------------------------
__device__ __forceinline__ float fwd_elem(
    float xfv, float gv, const float4* __restrict__ gq,
    float ss, float bal, float c2, int& imax_out)
{
    const float a1 = bal * gv;
    const float v0 = xfv + a1 * ss;
    int vm = (int)rintf(v0); vm = min(127, max(0, vm));
    const float dmv = v0 - (float)vm;
    const float Reff = sqrtf(30.0f / c2 + dmv * dmv);
    int lo = max(0, (int)ceilf(v0 - Reff));
    int hi = min(127, (int)floorf(v0 + Reff));
    lo = min(lo, vm); hi = max(hi, vm);

    const float dvm = (float)vm - xfv;
    const float mL = dvm * fmaf(-c2, dvm, a1);   // exact max logit (concavity)
    const int q0 = lo >> 2, qh = hi >> 2;        // qh - q0 <= 3
    float4 quad[4];
#pragma unroll
    for (int j = 0; j < 4; ++j) quad[j] = gq[min(q0 + j, qh)];

    float best = -1e30f; int imax = vm;
    float sum0 = 0.f, sum1 = 0.f;
#pragma unroll
    for (int j = 0; j < 4; ++j) {
        const int qi = q0 + j;
        const bool qok = qi <= qh;
        const float qs[4] = {quad[j].x, quad[j].y, quad[j].z, quad[j].w};
#pragma unroll
        for (int c = 0; c < 4; ++c) {
            int v = 4 * qi + c;
            bool ok = qok && v >= lo && v <= hi;
            float dv = (float)v - xfv;
            float lg = dv * fmaf(-c2, dv, a1);
            float y = ok ? (lg + qs[c]) : -1e30f;
            if (y > best) { best = y; imax = v; }   // ascending v, strict >: np.argmax
            float e = expf(lg - mL);
            if (c & 1) sum1 += ok ? e : 0.f; else sum0 += ok ? e : 0.f;
        }
    }
    float lse = mL + logf(sum0 + sum1);
    float dvc = (float)imax - xfv;
    float lch = dvc * fmaf(-c2, dvc, a1);
    imax_out = imax;
    return lch - lse;
}

// ---------------------------------------------------------------------------
// reverse per-element: windowed lse, gather at x_cur. Returns lch-lse.
// ---------------------------------------------------------------------------
__device__ __forceinline__ float rev_elem(
    float xdv, float gv, int xi, float ss, float bal, float c2)
{
    const float a1 = bal * gv;
    const float v0 = xdv + a1 * ss;
    int vm = (int)rintf(v0); vm = min(127, max(0, vm));
    const float dmv = v0 - (float)vm;
    const float Reff = sqrtf(30.0f / c2 + dmv * dmv);
    int lo = max(0, (int)ceilf(v0 - Reff));
    int hi = min(127, (int)floorf(v0 + Reff));
    lo = min(lo, vm); hi = max(hi, vm);

    const float dvm = (float)vm - xdv;
    const float mL = dvm * fmaf(-c2, dvm, a1);
    float sum0 = 0.f, sum1 = 0.f;
#pragma unroll
    for (int j = 0; j < 16; ++j) {       // span <= 12, predicated, full ILP
        int v = lo + j;
        bool ok = v <= hi;
        float dv = (float)v - xdv;
        float lg = dv * fmaf(-c2, dv, a1);
        float e = expf(lg - mL);
        if (j & 1) sum1 += ok ? e : 0.f; else sum0 += ok ? e : 0.f;
    }
    float lse = mL + logf(sum0 + sum1);
    float dvc = (float)xi - xdv;
    float lch = dvc * fmaf(-c2, dvc, a1);
    return lch - lse;
}

// ---------------------------------------------------------------------------
// One-time: Wsym = 0.5*(W + W^T) (32x32 LDS transpose tiles) + zero the
// producer-consumer counters (12 ints, re-zeroed every iteration).
// ---------------------------------------------------------------------------
__global__ __launch_bounds__(256) void symmetrize_k(
    const float* __restrict__ W, float* __restrict__ Wsym, int* cnt)
{
    if (blockIdx.x == 0 && blockIdx.y == 0 && threadIdx.x < 12)
        __hip_atomic_store(&cnt[threadIdx.x], 0, __ATOMIC_RELAXED, AGENT);
    __shared__ float tile[32][33];
    const int bx = blockIdx.x * 32, by = blockIdx.y * 32;
    const int tx = threadIdx.x & 31, ty4 = (threadIdx.x >> 5) * 4;
#pragma unroll
    for (int i = 0; i < 4; ++i) {
        int r = by + ty4 + i, c = bx + tx;
        tile[ty4 + i][tx] = (r < D_ && c < D_) ? W[r * D_ + c] : 0.f;
    }
    __syncthreads();
#pragma unroll
    for (int i = 0; i < 4; ++i) {
        int r = bx + ty4 + i, c = by + tx;       // tile[tx][ty4+i] == W[c][r]
        if (r < D_ && c < D_)
            Wsym[r * D_ + c] = 0.5f * (W[r * D_ + c] + tile[tx][ty4 + i]);
    }
}

// ---------------------------------------------------------------------------
// Producer: 64x64 tile, one K-slice of 98 (identical arithmetic/order to the
// round-1 split-K GEMM). Output via agent-scope stores so consumer blocks in
// the SAME launch can read it across XCDs (per-XCD L2s are not coherent).
// ---------------------------------------------------------------------------
__device__ __forceinline__ void gemm_tile_agent(
    const int* __restrict__ A, const float* __restrict__ Wsym,
    float* __restrict__ Cp, float* ldsbuf, int lt, int bt, int dt, int kz)
{
    float (*As)[20] = (float(*)[20])ldsbuf;
    float (*Ws)[68] = (float(*)[68])(ldsbuf + 64 * 20);
    const int k0 = kz * KC, kend = k0 + KC;
    const int tx = lt & 15, ty = lt >> 4;
    const int arow = lt >> 2, ac0 = (lt & 3) * 4;
    const int wrow = lt >> 4, wc0 = (lt & 15) * 4;
    const int wd0 = dt * 64 + wc0;

    float acc[4][4] = {};

    for (int kb = k0; kb < kend; kb += 16) {
#pragma unroll
        for (int c = 0; c < 4; ++c) {
            int k = kb + ac0 + c;
            As[arow][ac0 + c] = (k < kend) ? (float)A[(bt * 64 + arow) * D_ + k] : 0.f;
        }
        {
            int k = kb + wrow;
            float4 wv = (k < kend && wd0 < D_)
                ? *(const float4*)&Wsym[k * D_ + wd0]
                : make_float4(0.f, 0.f, 0.f, 0.f);
            *(float4*)&Ws[wrow][wc0] = wv;
        }
        __syncthreads();
#pragma unroll
        for (int kk = 0; kk < 16; kk += 4) {
            float va[4][4], vw[4][4];
#pragma unroll
            for (int i = 0; i < 4; ++i) {
                float4 t = *(const float4*)&As[ty * 4 + i][kk];
                va[i][0] = t.x; va[i][1] = t.y; va[i][2] = t.z; va[i][3] = t.w;
            }
#pragma unroll
            for (int m = 0; m < 4; ++m) {
                float4 t = *(const float4*)&Ws[kk + m][tx * 4];
                vw[m][0] = t.x; vw[m][1] = t.y; vw[m][2] = t.z; vw[m][3] = t.w;
            }
#pragma unroll
            for (int m = 0; m < 4; ++m)
#pragma unroll
                for (int i = 0; i < 4; ++i)
#pragma unroll
                    for (int j = 0; j < 4; ++j)
                        acc[i][j] = fmaf(va[i][m], vw[m][j], acc[i][j]);
        }
        __syncthreads();
    }

    const int d0 = dt * 64 + tx * 4;
    if (d0 < D_) {
#pragma unroll
        for (int i = 0; i < 4; ++i) {
            int bb = bt * 64 + ty * 4 + i;
            size_t base = (size_t)kz * BD + (size_t)bb * D_ + d0;
#pragma unroll
            for (int j = 0; j < 4; ++j)
                __hip_atomic_store(&Cp[base + j], acc[i][j], __ATOMIC_RELAXED, AGENT);
        }
    }
}

// ---------------------------------------------------------------------------
// Fused launch #1 kind: split-K GEMM producers (blocks 0..415) + forward
// consumers (blocks 416..671, one per batch row, spin on per-bt counter).
// ---------------------------------------------------------------------------
__global__ __launch_bounds__(256) void gemm_fwd_fused(
    const int* __restrict__ xin, const float* __restrict__ Wsym,
    const float* __restrict__ bvec, const float* __restrict__ gumbel,
    const int* __restrict__ kiter, int s,
    float* gpart, int* cnt,
    int* __restrict__ x_delta, double* __restrict__ lpf,
    double* __restrict__ Exf, float* __restrict__ gf)
{
    const int bid = blockIdx.x, tid = threadIdx.x;
    float ss, bal; get_params(kiter, ss, bal);
    const float c2 = 0.5f / ss;

    __shared__ __align__(16) float buf[SUBSZ];
    __shared__ double wred[4][2];

    if (bid < NJOBS) {
        const int kz = bid & 7, td = bid >> 3;
        const int dt = td % 13, bt = td / 13;
        gemm_tile_agent(xin, Wsym, gpart, buf, tid, bt, dt, kz);
        __syncthreads();   // all agent stores complete (vmcnt drained)
        if (tid == 0)
            __hip_atomic_fetch_add(&cnt[bt], 1, __ATOMIC_RELEASE, AGENT);
        return;
    }

    const int b = bid - NJOBS;
    if (tid == 0) {
        while (__hip_atomic_load(&cnt[b >> 6], __ATOMIC_ACQUIRE, AGENT) < JOBS_PER_BT)
            __builtin_amdgcn_s_sleep(2);
    }
    __syncthreads();

    double lp_acc = 0.0, e_acc = 0.0;
#pragma unroll
    for (int q = 0; q < 4; ++q) {
        const int d = tid + 256 * q;
        if (d < D_) {
            const int bd = b * D_ + d;
            const float xfv = (float)xin[bd];
            float gv = 0.f;
#pragma unroll
            for (int p = 0; p < KSPLIT; ++p)
                gv += __hip_atomic_load(&gpart[(size_t)p * BD + bd],
                                        __ATOMIC_RELAXED, AGENT);
            const float bvd = bvec[d];
            gv += bvd;
            const float4* gq =
                (const float4*)(gumbel + (((size_t)s * B_ + b) * D_ + d) * V_);
            int imax;
            float lp = fwd_elem(xfv, gv, gq, ss, bal, c2, imax);
            lp_acc += (double)lp;
            e_acc  += (double)xfv * ((double)gv + (double)bvd);
            x_delta[bd] = imax;
            gf[bd] = gv;     // gradient (incl. b) for step-1 reuse
        }
    }
    const int lane = tid & 63, wv = tid >> 6;
    double t = wave_red(lp_acc);
    if (lane == 0) wred[wv][0] = t;
    t = wave_red(e_acc);
    if (lane == 0) wred[wv][1] = t;
    __syncthreads();
    if (tid == 0) {
        double sl = 0, se = 0;
#pragma unroll
        for (int i = 0; i < 4; ++i) { sl += wred[i][0]; se += wred[i][1]; }
        lpf[b] = sl; Exf[b] = se;
    }
}

// ---------------------------------------------------------------------------
// Fused launch #2 kind: GEMM(x_delta) producers + reverse consumers.
// Non-last: writes gsel = accept ? grad(x_delta) : grad(x_cur) for g-reuse.
// ---------------------------------------------------------------------------
__global__ __launch_bounds__(256) void gemm_rev_fused(
    const int* __restrict__ xin, int* __restrict__ x_cur,
    const int* __restrict__ x_delta, const float* __restrict__ Wsym,
    const float* __restrict__ bvec, const float* __restrict__ u,
    const int* __restrict__ kiter, int s, int last,
    float* gpart, int* cnt,
    const double* __restrict__ lpf, const double* __restrict__ Exf,
    const float* __restrict__ gf, float* __restrict__ gsel,
    float* __restrict__ out)
{
    const int bid = blockIdx.x, tid = threadIdx.x;
    float ss, bal; get_params(kiter, ss, bal);
    const float c2 = 0.5f / ss;

    __shared__ __align__(16) float buf[SUBSZ];
    __shared__ double wred[4][2];
    __shared__ int acc_s;
    __shared__ float la_s;

    if (bid < NJOBS) {
        const int kz = bid & 7, td = bid >> 3;
        const int dt = td % 13, bt = td / 13;
        gemm_tile_agent(x_delta, Wsym, gpart, buf, tid, bt, dt, kz);
        __syncthreads();
        if (tid == 0)
            __hip_atomic_fetch_add(&cnt[bt], 1, __ATOMIC_RELEASE, AGENT);
        return;
    }

    const int b = bid - NJOBS;
    if (tid == 0) {
        while (__hip_atomic_load(&cnt[b >> 6], __ATOMIC_ACQUIRE, AGENT) < JOBS_PER_BT)
            __builtin_amdgcn_s_sleep(2);
    }
    __syncthreads();

    double lp_acc = 0.0, e_acc = 0.0;
    float gv_sav[4]; int xi_sav[4], xd_sav[4];
#pragma unroll
    for (int q = 0; q < 4; ++q) {
        const int d = tid + 256 * q;
        if (d < D_) {
            const int bd = b * D_ + d;
            const int xi = xin[bd];
            const int xd = x_delta[bd];
            const float xdv = (float)xd;
            float gv = 0.f;
#pragma unroll
            for (int p = 0; p < KSPLIT; ++p)
                gv += __hip_atomic_load(&gpart[(size_t)p * BD + bd],
                                        __ATOMIC_RELAXED, AGENT);
            const float bvd = bvec[d];
            gv += bvd;
            gv_sav[q] = gv; xi_sav[q] = xi; xd_sav[q] = xd;
            float lp = rev_elem(xdv, gv, xi, ss, bal, c2);
            lp_acc += (double)lp;
            e_acc  += (double)xdv * ((double)gv + (double)bvd);
        }
    }
    const int lane = tid & 63, wv = tid >> 6;
    double t = wave_red(lp_acc);
    if (lane == 0) wred[wv][0] = t;
    t = wave_red(e_acc);
    if (lane == 0) wred[wv][1] = t;
    __syncthreads();
    if (tid == 0) {
        double lpr = 0, exd = 0;
#pragma unroll
        for (int i = 0; i < 4; ++i) { lpr += wred[i][0]; exd += wred[i][1]; }
        double la = 0.5 * (exd - Exf[b]) + lpr - lpf[b];
        acc_s = (exp(la) > (double)u[s * B_ + b]) ? 1 : 0;
        la_s = (float)la;
    }
    __syncthreads();

    const int acc = acc_s;
#pragma unroll
    for (int q = 0; q < 4; ++q) {
        const int d = tid + 256 * q;
        if (d < D_) {
            const int bd = b * D_ + d;
            int xn = acc ? xd_sav[q] : xi_sav[q];
            x_cur[bd] = xn;
            if (!last) gsel[bd] = acc ? gv_sav[q] : gf[bd];
            else       out[bd] = (float)xn;
        }
    }
    if (last && tid == 0) out[BD + b] = la_s;
}

// ---------------------------------------------------------------------------
// Step-1 forward: NO GEMM — reads the reused gradient gsel (bitwise equal to
// recomputing grad(x_new), since the GEMM is a pure function of the int x).
// ---------------------------------------------------------------------------
__global__ __launch_bounds__(832) void forward2_k(
    const int* __restrict__ xin, const float* __restrict__ gsel,
    const float* __restrict__ bvec, const float* __restrict__ gumbel,
    const int* __restrict__ kiter, int s,
    int* __restrict__ x_delta, double* __restrict__ lpf, double* __restrict__ Exf)
{
    const int b = blockIdx.x, tid = threadIdx.x;
    float ss, bal; get_params(kiter, ss, bal);
    const float c2 = 0.5f / ss;
    double lp_acc = 0.0, e_acc = 0.0;
    if (tid < D_) {
        const int d = tid, bd = b * D_ + d;
        const float xfv = (float)xin[bd];
        const float gv = gsel[bd];
        const float bvd = bvec[d];
        const float4* gq =
            (const float4*)(gumbel + (((size_t)s * B_ + b) * D_ + d) * V_);
        int imax;
        float lp = fwd_elem(xfv, gv, gq, ss, bal, c2, imax);
        lp_acc = (double)lp;
        e_acc  = (double)xfv * ((double)gv + (double)bvd);
        x_delta[bd] = imax;
    }
    __shared__ double wred[13][2];
    const int lane = tid & 63, wv = tid >> 6;
    double t = wave_red(lp_acc);
    if (lane == 0) wred[wv][0] = t;
    t = wave_red(e_acc);
    if (lane == 0) wred[wv][1] = t;
    __syncthreads();
    if (tid == 0) {
        double sl = 0, se = 0;
        for (int i = 0; i < 13; ++i) { sl += wred[i][0]; se += wred[i][1]; }
        lpf[b] = sl; Exf[b] = se;
    }
}

// ---------------------------------------------------------------------------
extern "C" void kernel_launch(void* const* d_in, const int* in_sizes, int n_in,
                              void* d_out, int out_size, void* d_ws, size_t ws_size,
                              hipStream_t stream)
{
    const int*   x     = (const int*)d_in[0];
    const float* W     = (const float*)d_in[1];
    const float* bv    = (const float*)d_in[2];
    const float* gum   = (const float*)d_in[3];
    const float* u     = (const float*)d_in[4];
    const int*   kiter = (const int*)d_in[5];
    float* out = (float*)d_out;

    char* w = (char*)d_ws;
    size_t off = 0;
    auto carve = [&](size_t bytes) { void* p = w + off; off += (bytes + 511) & ~511ull; return p; };
    int*    x_cur   = (int*)   carve((size_t)BD * 4);
    int*    x_delta = (int*)   carve((size_t)BD * 4);
    float*  gpart   = (float*) carve((size_t)KSPLIT * BD * 4);
    float*  Wsym    = (float*) carve((size_t)D_ * D_ * 4);
    float*  gf      = (float*) carve((size_t)BD * 4);
    float*  gsel    = (float*) carve((size_t)BD * 4);
    double* lpf     = (double*)carve(B_ * 8);
    double* Exf     = (double*)carve(B_ * 8);
    int*    cnt     = (int*)   carve(12 * 4);
    (void)ws_size; (void)in_sizes; (void)n_in; (void)out_size;

    // 5 launches total (was 9): sym, {G+fwd}0, {G+rev}0, fwd1(g-reuse), {G+rev}1
    symmetrize_k<<<dim3(25, 25), 256, 0, stream>>>(W, Wsym, cnt);

    gemm_fwd_fused<<<NBLK_FUSED, 256, 0, stream>>>(
        x, Wsym, bv, gum, kiter, 0, gpart, cnt + 0, x_delta, lpf, Exf, gf);

    gemm_rev_fused<<<NBLK_FUSED, 256, 0, stream>>>(
        x, x_cur, x_delta, Wsym, bv, u, kiter, 0, 0,
        gpart, cnt + 4, lpf, Exf, gf, gsel, out);

    forward2_k<<<B_, 832, 0, stream>>>(
        x_cur, gsel, bv, gum, kiter, 1, x_delta, lpf, Exf);

    gemm_rev_fused<<<NBLK_FUSED, 256, 0, stream>>>(
        x_cur, x_cur, x_delta, Wsym, bv, u, kiter, 1, 1,
        gpart, cnt + 8, lpf, Exf, gf, gsel, out);
}

// Round 7
// 334.337 us; speedup vs baseline: 2.1597x; 2.1597x over previous
//
#include <hip/hip_runtime.h>

#define B_ 256
#define D_ 784
#define V_ 128
#define S_ 2
#define BD (B_ * D_)
#define KSPLIT 8
#define KC 98      // 784 / KSPLIT

__device__ __forceinline__ void get_params(const int* kiter, float& ss, float& bal) {
    int k = kiter[0] % 10;
    ss  = (k == 0) ? 0.5f : 0.1f;
    bal = (k == 0) ? 0.9f : 0.6f;
}

__device__ __forceinline__ double wave_red(double v) {
#pragma unroll
    for (int o = 32; o > 0; o >>= 1) v += __shfl_down(v, o, 64);
    return v;
}

// ---------------------------------------------------------------------------
// One-time: Wsym[r][c] = 0.5*(W[r][c] + W[c][r]). 32x32 LDS transpose tiles.
// ---------------------------------------------------------------------------
__global__ __launch_bounds__(256) void symmetrize_k(
    const float* __restrict__ W, float* __restrict__ Wsym)
{
    __shared__ float tile[32][33];
    const int bx = blockIdx.x * 32, by = blockIdx.y * 32;
    const int tx = threadIdx.x & 31, ty4 = (threadIdx.x >> 5) * 4;
#pragma unroll
    for (int i = 0; i < 4; ++i) {
        int r = by + ty4 + i, c = bx + tx;
        tile[ty4 + i][tx] = (r < D_ && c < D_) ? W[r * D_ + c] : 0.f;
    }
    __syncthreads();
#pragma unroll
    for (int i = 0; i < 4; ++i) {
        int r = bx + ty4 + i, c = by + tx;       // tile[tx][ty4+i] == W[c][r]
        if (r < D_ && c < D_)
            Wsym[r * D_ + c] = 0.5f * (W[r * D_ + c] + tile[tx][ty4 + i]);
    }
}

// ---------------------------------------------------------------------------
// split-K GEMM (round-1 proven): Cp[kz][b][d] = sum_{k slice} A[b][k]*Wsym[k][d]
// 64x64 tiles, kc=16, KSPLIT=8. Deterministic accumulation order.
// ---------------------------------------------------------------------------
__global__ __launch_bounds__(256) void gemm_splitk(
    const int* __restrict__ Aint, const float* __restrict__ Wsym,
    float* __restrict__ Cp)
{
    const int bt = blockIdx.x, dt = blockIdx.y, kz = blockIdx.z;
    const int tid = threadIdx.x;
    const int k0 = kz * KC, kend = k0 + KC;

    __shared__ float As[64][20];
    __shared__ float Ws[16][68];

    const int tx = tid & 15, ty = tid >> 4;
    const int arow = tid >> 2, ac0 = (tid & 3) * 4;
    const int wrow = tid >> 4, wc0 = (tid & 15) * 4;
    const int wd0 = dt * 64 + wc0;

    float acc[4][4] = {};

    for (int kb = k0; kb < kend; kb += 16) {
#pragma unroll
        for (int c = 0; c < 4; ++c) {
            int k = kb + ac0 + c;
            As[arow][ac0 + c] = (k < kend) ? (float)Aint[(bt * 64 + arow) * D_ + k] : 0.f;
        }
        {
            int k = kb + wrow;
            float4 wv = (k < kend && wd0 < D_)
                ? *(const float4*)&Wsym[k * D_ + wd0]
                : make_float4(0.f, 0.f, 0.f, 0.f);
            *(float4*)&Ws[wrow][wc0] = wv;
        }
        __syncthreads();
#pragma unroll
        for (int kk = 0; kk < 16; kk += 4) {
            float va[4][4], vw[4][4];
#pragma unroll
            for (int i = 0; i < 4; ++i) {
                float4 t = *(const float4*)&As[ty * 4 + i][kk];
                va[i][0] = t.x; va[i][1] = t.y; va[i][2] = t.z; va[i][3] = t.w;
            }
#pragma unroll
            for (int m = 0; m < 4; ++m) {
                float4 t = *(const float4*)&Ws[kk + m][tx * 4];
                vw[m][0] = t.x; vw[m][1] = t.y; vw[m][2] = t.z; vw[m][3] = t.w;
            }
#pragma unroll
            for (int m = 0; m < 4; ++m)
#pragma unroll
                for (int i = 0; i < 4; ++i)
#pragma unroll
                    for (int j = 0; j < 4; ++j)
                        acc[i][j] = fmaf(va[i][m], vw[m][j], acc[i][j]);
        }
        __syncthreads();
    }

    const int d0 = dt * 64 + tx * 4;
    if (d0 < D_) {
#pragma unroll
        for (int i = 0; i < 4; ++i) {
            int bb = bt * 64 + ty * 4 + i;
            *(float4*)&Cp[(size_t)kz * BD + (size_t)bb * D_ + d0] =
                make_float4(acc[i][0], acc[i][1], acc[i][2], acc[i][3]);
        }
    }
}

// ---------------------------------------------------------------------------
// forward (s=0): g-reduce + windowed categorical + lse; ALSO stores the full
// gradient gf[bd] = g+b for step-1 reuse.
// ---------------------------------------------------------------------------
__global__ __launch_bounds__(832) void forward_k(
    const int* __restrict__ xin, const float* __restrict__ gpart,
    const float* __restrict__ bvec, const float* __restrict__ gumbel,
    const int* __restrict__ kiter, int s,
    int* __restrict__ x_delta, double* __restrict__ lpf, double* __restrict__ Exf,
    float* __restrict__ gf)
{
    const int b = blockIdx.x, tid = threadIdx.x;
    float ss, bal; get_params(kiter, ss, bal);
    const float c2 = 0.5f / ss;

    double lp_acc = 0.0, e_acc = 0.0;

    if (tid < D_) {
        const int d = tid, bd = b * D_ + d;
        const int xi = xin[bd];
        const float xfv = (float)xi;

        float gv = 0.f;
#pragma unroll
        for (int p = 0; p < KSPLIT; ++p) gv += gpart[(size_t)p * BD + bd];
        gv += bvec[d];
        gf[bd] = gv;                              // reuse in step 1

        const float a1 = bal * gv;
        const float v0 = xfv + a1 * ss;
        int vm = (int)rintf(v0); vm = min(127, max(0, vm));
        const float dmv = v0 - (float)vm;
        const float Reff = sqrtf(30.0f / c2 + dmv * dmv);
        int lo = max(0, (int)ceilf(v0 - Reff));
        int hi = min(127, (int)floorf(v0 + Reff));
        lo = min(lo, vm); hi = max(hi, vm);

        const float dvm = (float)vm - xfv;
        const float mL = dvm * fmaf(-c2, dvm, a1);   // exact max logit (concavity)

        const float4* __restrict__ gq =
            (const float4*)(gumbel + (((size_t)s * B_ + b) * D_ + d) * V_);
        const int q0 = lo >> 2, qh = hi >> 2;        // qh - q0 <= 3
        float4 quad[4];
#pragma unroll
        for (int j = 0; j < 4; ++j) quad[j] = gq[min(q0 + j, qh)];

        float best = -1e30f; int imax = vm;
        float sum0 = 0.f, sum1 = 0.f;
#pragma unroll
        for (int j = 0; j < 4; ++j) {
            const int qi = q0 + j;
            const bool qok = qi <= qh;
            const float qs[4] = {quad[j].x, quad[j].y, quad[j].z, quad[j].w};
#pragma unroll
            for (int c = 0; c < 4; ++c) {
                int v = 4 * qi + c;
                bool ok = qok && v >= lo && v <= hi;
                float dv = (float)v - xfv;
                float lg = dv * fmaf(-c2, dv, a1);
                float y = ok ? (lg + qs[c]) : -1e30f;
                if (y > best) { best = y; imax = v; }   // ascending v, strict >: np.argmax
                float e = expf(lg - mL);
                if (c & 1) sum1 += ok ? e : 0.f; else sum0 += ok ? e : 0.f;
            }
        }
        float lse = mL + logf(sum0 + sum1);
        float dvc = (float)imax - xfv;
        float lch = dvc * fmaf(-c2, dvc, a1);
        lp_acc = (double)(lch - lse);
        e_acc  = (double)xfv * ((double)gv + (double)bvec[d]);
        x_delta[bd] = imax;
    }

    __shared__ double wred[13];
    const int lane = tid & 63, wv = tid >> 6;
    double t = wave_red(lp_acc);
    if (lane == 0) wred[wv] = t;
    __syncthreads();
    if (tid == 0) { double sm = 0; for (int i = 0; i < 13; ++i) sm += wred[i]; lpf[b] = sm; }
    __syncthreads();
    t = wave_red(e_acc);
    if (lane == 0) wred[wv] = t;
    __syncthreads();
    if (tid == 0) { double sm = 0; for (int i = 0; i < 13; ++i) sm += wred[i]; Exf[b] = sm; }
}

// ---------------------------------------------------------------------------
// forward (s=1): NO GEMM — reads reused gradient gsel (bitwise equal to
// recomputing, since the split-K GEMM is a pure per-row function of int x).
// ---------------------------------------------------------------------------
__global__ __launch_bounds__(832) void forward2_k(
    const int* __restrict__ xin, const float* __restrict__ gsel,
    const float* __restrict__ bvec, const float* __restrict__ gumbel,
    const int* __restrict__ kiter, int s,
    int* __restrict__ x_delta, double* __restrict__ lpf, double* __restrict__ Exf)
{
    const int b = blockIdx.x, tid = threadIdx.x;
    float ss, bal; get_params(kiter, ss, bal);
    const float c2 = 0.5f / ss;

    double lp_acc = 0.0, e_acc = 0.0;

    if (tid < D_) {
        const int d = tid, bd = b * D_ + d;
        const float xfv = (float)xin[bd];
        const float gv = gsel[bd];                // g+b, selected in reverse_k(s=0)

        const float a1 = bal * gv;
        const float v0 = xfv + a1 * ss;
        int vm = (int)rintf(v0); vm = min(127, max(0, vm));
        const float dmv = v0 - (float)vm;
        const float Reff = sqrtf(30.0f / c2 + dmv * dmv);
        int lo = max(0, (int)ceilf(v0 - Reff));
        int hi = min(127, (int)floorf(v0 + Reff));
        lo = min(lo, vm); hi = max(hi, vm);

        const float dvm = (float)vm - xfv;
        const float mL = dvm * fmaf(-c2, dvm, a1);

        const float4* __restrict__ gq =
            (const float4*)(gumbel + (((size_t)s * B_ + b) * D_ + d) * V_);
        const int q0 = lo >> 2, qh = hi >> 2;
        float4 quad[4];
#pragma unroll
        for (int j = 0; j < 4; ++j) quad[j] = gq[min(q0 + j, qh)];

        float best = -1e30f; int imax = vm;
        float sum0 = 0.f, sum1 = 0.f;
#pragma unroll
        for (int j = 0; j < 4; ++j) {
            const int qi = q0 + j;
            const bool qok = qi <= qh;
            const float qs[4] = {quad[j].x, quad[j].y, quad[j].z, quad[j].w};
#pragma unroll
            for (int c = 0; c < 4; ++c) {
                int v = 4 * qi + c;
                bool ok = qok && v >= lo && v <= hi;
                float dv = (float)v - xfv;
                float lg = dv * fmaf(-c2, dv, a1);
                float y = ok ? (lg + qs[c]) : -1e30f;
                if (y > best) { best = y; imax = v; }
                float e = expf(lg - mL);
                if (c & 1) sum1 += ok ? e : 0.f; else sum0 += ok ? e : 0.f;
            }
        }
        float lse = mL + logf(sum0 + sum1);
        float dvc = (float)imax - xfv;
        float lch = dvc * fmaf(-c2, dvc, a1);
        lp_acc = (double)(lch - lse);
        e_acc  = (double)xfv * ((double)gv + (double)bvec[d]);
        x_delta[bd] = imax;
    }

    __shared__ double wred[13];
    const int lane = tid & 63, wv = tid >> 6;
    double t = wave_red(lp_acc);
    if (lane == 0) wred[wv] = t;
    __syncthreads();
    if (tid == 0) { double sm = 0; for (int i = 0; i < 13; ++i) sm += wred[i]; lpf[b] = sm; }
    __syncthreads();
    t = wave_red(e_acc);
    if (lane == 0) wred[wv] = t;
    __syncthreads();
    if (tid == 0) { double sm = 0; for (int i = 0; i < 13; ++i) sm += wred[i]; Exf[b] = sm; }
}

// ---------------------------------------------------------------------------
// reverse: g-reduce + windowed lse + MH accept + x update. On s=0 also writes
// gsel = accept ? g(x_delta) : gf  (the gradient of x_new, for step-1 reuse).
// ---------------------------------------------------------------------------
__global__ __launch_bounds__(832) void reverse_k(
    const int* __restrict__ xin, int* __restrict__ x_cur,
    const int* __restrict__ x_delta,
    const float* __restrict__ gpart, const float* __restrict__ bvec,
    const float* __restrict__ u, const int* __restrict__ kiter,
    int s, int last, const double* __restrict__ lpf, const double* __restrict__ Exf,
    const float* __restrict__ gf, float* __restrict__ gsel,
    float* __restrict__ out)
{
    const int b = blockIdx.x, tid = threadIdx.x;
    float ss, bal; get_params(kiter, ss, bal);
    const float c2 = 0.5f / ss;

    double lp_acc = 0.0, e_acc = 0.0;
    float gv_sav = 0.f;
    int xi_sav = 0, xd_sav = 0;

    if (tid < D_) {
        const int d = tid, bd = b * D_ + d;
        const int xi = xin[bd];
        const int xd = x_delta[bd];
        const float xdv = (float)xd;
        xi_sav = xi; xd_sav = xd;

        float gv = 0.f;
#pragma unroll
        for (int p = 0; p < KSPLIT; ++p) gv += gpart[(size_t)p * BD + bd];
        gv += bvec[d];
        gv_sav = gv;

        const float a1 = bal * gv;
        const float v0 = xdv + a1 * ss;
        int vm = (int)rintf(v0); vm = min(127, max(0, vm));
        const float dmv = v0 - (float)vm;
        const float Reff = sqrtf(30.0f / c2 + dmv * dmv);
        int lo = max(0, (int)ceilf(v0 - Reff));
        int hi = min(127, (int)floorf(v0 + Reff));
        lo = min(lo, vm); hi = max(hi, vm);

        const float dvm = (float)vm - xdv;
        const float mL = dvm * fmaf(-c2, dvm, a1);
        float sum0 = 0.f, sum1 = 0.f;
#pragma unroll
        for (int j = 0; j < 16; ++j) {       // span <= 12, predicated, full ILP
            int v = lo + j;
            bool ok = v <= hi;
            float dv = (float)v - xdv;
            float lg = dv * fmaf(-c2, dv, a1);
            float e = expf(lg - mL);
            if (j & 1) sum1 += ok ? e : 0.f; else sum0 += ok ? e : 0.f;
        }
        float lse = mL + logf(sum0 + sum1);
        float dvc = (float)xi - xdv;                 // logp_d gathered at x_cur
        float lch = dvc * fmaf(-c2, dvc, a1);
        lp_acc = (double)(lch - lse);
        e_acc  = (double)xdv * ((double)gv + (double)bvec[d]);
    }

    __shared__ double wred[13];
    __shared__ int accept_s;
    __shared__ float la_s;
    const int lane = tid & 63, wv = tid >> 6;

    double t = wave_red(lp_acc);
    if (lane == 0) wred[wv] = t;
    __syncthreads();
    double lpr = 0;
    if (tid == 0) { for (int i = 0; i < 13; ++i) lpr += wred[i]; }
    __syncthreads();
    t = wave_red(e_acc);
    if (lane == 0) wred[wv] = t;
    __syncthreads();
    if (tid == 0) {
        double exd = 0; for (int i = 0; i < 13; ++i) exd += wred[i];
        double la = 0.5 * (exd - Exf[b]) + lpr - lpf[b];
        accept_s = (exp(la) > (double)u[s * B_ + b]) ? 1 : 0;
        la_s = (float)la;
    }
    __syncthreads();

    const int acc = accept_s;
    if (tid < D_) {
        const int bd = b * D_ + tid;
        int xn = acc ? xd_sav : xi_sav;
        x_cur[bd] = xn;
        if (!last) gsel[bd] = acc ? gv_sav : gf[bd];
        else       out[bd] = (float)xn;
    }
    if (last && tid == 0) out[BD + b] = la_s;
}

// ---------------------------------------------------------------------------
extern "C" void kernel_launch(void* const* d_in, const int* in_sizes, int n_in,
                              void* d_out, int out_size, void* d_ws, size_t ws_size,
                              hipStream_t stream)
{
    const int*   x     = (const int*)d_in[0];
    const float* W     = (const float*)d_in[1];
    const float* bv    = (const float*)d_in[2];
    const float* gum   = (const float*)d_in[3];
    const float* u     = (const float*)d_in[4];
    const int*   kiter = (const int*)d_in[5];
    float* out = (float*)d_out;

    char* w = (char*)d_ws;
    size_t off = 0;
    auto carve = [&](size_t bytes) { void* p = w + off; off += (bytes + 511) & ~511ull; return p; };
    int*    x_cur   = (int*)   carve((size_t)BD * 4);
    int*    x_delta = (int*)   carve((size_t)BD * 4);
    float*  gpart   = (float*) carve((size_t)KSPLIT * BD * 4);
    float*  Wsym    = (float*) carve((size_t)D_ * D_ * 4);
    float*  gf      = (float*) carve((size_t)BD * 4);
    float*  gsel    = (float*) carve((size_t)BD * 4);
    double* lpf     = (double*)carve(B_ * 8);
    double* Exf     = (double*)carve(B_ * 8);
    (void)ws_size; (void)in_sizes; (void)n_in; (void)out_size;

    // 8 launches (was 9): sym | G(x) | fwd0 | G(xd) | rev0 | fwd1(g-reuse) | G(xd) | rev1
    symmetrize_k<<<dim3(25, 25), 256, 0, stream>>>(W, Wsym);

    // step 0
    gemm_splitk<<<dim3(4, 13, KSPLIT), 256, 0, stream>>>(x, Wsym, gpart);
    forward_k<<<B_, 832, 0, stream>>>(x, gpart, bv, gum, kiter, 0, x_delta, lpf, Exf, gf);
    gemm_splitk<<<dim3(4, 13, KSPLIT), 256, 0, stream>>>(x_delta, Wsym, gpart);
    reverse_k<<<B_, 832, 0, stream>>>(x, x_cur, x_delta, gpart, bv, u, kiter, 0, 0,
                                      lpf, Exf, gf, gsel, out);

    // step 1 — forward GEMM eliminated via gsel
    forward2_k<<<B_, 832, 0, stream>>>(x_cur, gsel, bv, gum, kiter, 1, x_delta, lpf, Exf);
    gemm_splitk<<<dim3(4, 13, KSPLIT), 256, 0, stream>>>(x_delta, Wsym, gpart);
    reverse_k<<<B_, 832, 0, stream>>>(x_cur, x_cur, x_delta, gpart, bv, u, kiter, 1, 1,
                                      lpf, Exf, gf, gsel, out);
}